// Round 1
// baseline (2339.612 us; speedup 1.0000x reference)
//
#include <hip/hip_runtime.h>
#include <hip/hip_fp16.h>

#define NB 256
#define NT 1024
#define NH 256
#define NL 128
#define NV 13

typedef _Float16 h2t __attribute__((ext_vector_type(2)));
typedef _Float16 f16x8 __attribute__((ext_vector_type(8)));
typedef float f32x4 __attribute__((ext_vector_type(4)));

#define WS_WHH   0x0u       // u32[1024][128]  512KB  packed f16 W_hh
#define WS_WIH   0x80000u   // u32[1024][8]    32KB   packed f16 W_ih (padded 13->16)
#define WS_BIAS  0x88000u   // f32[1024]       4KB    b_ih+b_hh
#define WS_H0F   0x89000u   // u32[256][128]   128KB  packed f16 h0
#define WS_LATF  0xA9000u   // u32[256][64]    64KB   packed f16 latent
#define WS_WNL   0xB9000u   // u32[256][192]   192KB  packed f16 W_nl
#define WS_WOUT  0xE9000u   // u32[16][128]    8KB    packed f16 W_out (padded 13->16 rows)
#define WS_HS    0x100000u  // f16[256][1024][256] = 128MB hidden states

__device__ __forceinline__ unsigned pk2(float a, float b){
  union { h2t h; unsigned u; } u;
  u.h.x = (_Float16)a; u.h.y = (_Float16)b;
  return u.u;
}

__device__ __forceinline__ float fdot2u(unsigned a, unsigned b, float c){
#if __has_builtin(__builtin_amdgcn_fdot2)
  union { unsigned u; h2t h; } ua, ub;
  ua.u = a; ub.u = b;
  return __builtin_amdgcn_fdot2(ua.h, ub.h, c, false);
#else
  union { unsigned u; h2t h; } ua, ub;
  ua.u = a; ub.u = b;
  return c + (float)ua.h.x*(float)ub.h.x + (float)ua.h.y*(float)ub.h.y;
#endif
}

__device__ __forceinline__ float sigm(float x){ return __builtin_amdgcn_rcpf(1.f + __expf(-x)); }
__device__ __forceinline__ float tanh_(float x){ return 2.f*__builtin_amdgcn_rcpf(1.f + __expf(-2.f*x)) - 1.f; }

// ---------------- prep: pack weights to f16 ----------------
__global__ void k_prep(const float* __restrict__ Wih, const float* __restrict__ Whh,
                       const float* __restrict__ bih, const float* __restrict__ bhh,
                       const float* __restrict__ Wnl, const float* __restrict__ Wout,
                       unsigned char* __restrict__ ws){
  unsigned* whh = (unsigned*)(ws + WS_WHH);
  unsigned* wih = (unsigned*)(ws + WS_WIH);
  float* bias   = (float*)(ws + WS_BIAS);
  unsigned* wnl = (unsigned*)(ws + WS_WNL);
  unsigned* wout= (unsigned*)(ws + WS_WOUT);
  int blk = blockIdx.x, tid = threadIdx.x;
  if (blk < 1024){
    int r = blk;
    if (tid < 128) whh[r*128+tid] = pk2(Whh[r*256+2*tid], Whh[r*256+2*tid+1]);
    if (tid < 8){
      int k0 = 2*tid, k1 = 2*tid+1;
      float a = (k0 < NV)? Wih[r*NV+k0] : 0.f;
      float b = (k1 < NV)? Wih[r*NV+k1] : 0.f;
      wih[r*8+tid] = pk2(a,b);
    }
    if (tid == 0) bias[r] = bih[r] + bhh[r];
  } else if (blk < 1280){
    int n = blk - 1024;
    for (int i = tid; i < 192; i += 128)
      wnl[n*192+i] = pk2(Wnl[n*384+2*i], Wnl[n*384+2*i+1]);
  } else {
    for (int i = tid; i < 2048; i += 128){
      int v = i >> 7; int p = (i & 127)*2;
      float a = (v < NV)? Wout[v*256+p]   : 0.f;
      float b = (v < NV)? Wout[v*256+p+1] : 0.f;
      wout[i] = pk2(a,b);
    }
  }
}

// ---------------- init: h0 = relu(lat @ W_lat^T + b), pack lat, zero out ----------------
__global__ void k_init(const float* __restrict__ lat, const float* __restrict__ Wlat,
                       const float* __restrict__ blat, unsigned char* __restrict__ ws,
                       float* __restrict__ out){
  __shared__ float sl[NL];
  __shared__ float h0[NH];
  int b = blockIdx.x, j = threadIdx.x;
  if (j < NL) sl[j] = lat[b*NL+j];
  __syncthreads();
  float a = blat[j];
  for (int k = 0; k < NL; ++k) a += Wlat[j*NL+k]*sl[k];
  h0[j] = a > 0.f ? a : 0.f;
  __syncthreads();
  unsigned* h0f  = (unsigned*)(ws + WS_H0F);
  unsigned* latf = (unsigned*)(ws + WS_LATF);
  if (j < 128) h0f[b*128+j] = pk2(h0[2*j], h0[2*j+1]);
  if (j < 64)  latf[b*64+j] = pk2(sl[2*j], sl[2*j+1]);
  if (j == 0)  out[b] = 0.f;
}

// ---------------- recurrent LSTM: 1 workgroup per batch element ----------------
// 512 threads; thread j owns gate rows j and j+512.
// W_hh row (256 f16): k=0..191 in registers (48 uint4/thread for 2 rows), k=192..255 in LDS.
__global__ __launch_bounds__(512, 2)
void k_lstm(const float* __restrict__ seq, unsigned char* __restrict__ ws){
  __shared__ __align__(16) unsigned lw[1024*36];   // 144KB: [row][32 u32 + 4 pad]
  __shared__ __align__(16) unsigned h2[128];       // packed f16 h
  __shared__ float gts[1024];
  __shared__ unsigned xb[2][8];                    // packed f16 x_t (13 padded to 16)
  int b = blockIdx.x, j = threadIdx.x;
  int r0 = j, r1 = j + 512;
  const uint4* whh4 = (const uint4*)(ws + WS_WHH);   // 32 uint4 per row
  const uint4* wih4 = (const uint4*)(ws + WS_WIH);   // 2 uint4 per row
  const float* bias = (const float*)(ws + WS_BIAS);
  const unsigned* h0f = (const unsigned*)(ws + WS_H0F);
  __half* hs = (__half*)(ws + WS_HS);

  uint4 w0v[24], w1v[24];
#pragma unroll
  for (int i = 0; i < 24; ++i){ w0v[i] = whh4[r0*32+i]; w1v[i] = whh4[r1*32+i]; }
  uint4* lw4 = (uint4*)lw;   // 9 uint4 stride per row (8 used + 1 pad)
#pragma unroll
  for (int i = 0; i < 8; ++i){ lw4[r0*9+i] = whh4[r0*32+24+i]; lw4[r1*9+i] = whh4[r1*32+24+i]; }
  uint4 wi0a = wih4[r0*2], wi0b = wih4[r0*2+1];
  uint4 wi1a = wih4[r1*2], wi1b = wih4[r1*2+1];
  float bb0 = bias[r0], bb1 = bias[r1];
  if (j < 128) h2[j] = h0f[b*128+j];
  if (j >= 256 && j < 264){
    int i2 = j - 256; int k0 = 2*i2;
    const float* xp = seq + (size_t)b*NT*NV;
    float xa = (k0   < NV)? xp[k0]   : 0.f;
    float xc = (k0+1 < NV)? xp[k0+1] : 0.f;
    xb[0][i2] = pk2(xa, xc);
  }
  float c = 0.f;
  __syncthreads();
  const uint4* h2v = (const uint4*)h2;

#pragma unroll 1
  for (int t = 0; t < NT; ++t){
    float a0 = bb0, a1 = bb1;
    {
      const unsigned* xc = xb[t & 1];
      a0 = fdot2u(wi0a.x, xc[0], a0); a0 = fdot2u(wi0a.y, xc[1], a0);
      a0 = fdot2u(wi0a.z, xc[2], a0); a0 = fdot2u(wi0a.w, xc[3], a0);
      a0 = fdot2u(wi0b.x, xc[4], a0); a0 = fdot2u(wi0b.y, xc[5], a0);
      a0 = fdot2u(wi0b.z, xc[6], a0);
      a1 = fdot2u(wi1a.x, xc[0], a1); a1 = fdot2u(wi1a.y, xc[1], a1);
      a1 = fdot2u(wi1a.z, xc[2], a1); a1 = fdot2u(wi1a.w, xc[3], a1);
      a1 = fdot2u(wi1b.x, xc[4], a1); a1 = fdot2u(wi1b.y, xc[5], a1);
      a1 = fdot2u(wi1b.z, xc[6], a1);
    }
#pragma unroll
    for (int q = 0; q < 24; ++q){
      uint4 hq = h2v[q];
      a0 = fdot2u(w0v[q].x, hq.x, a0); a0 = fdot2u(w0v[q].y, hq.y, a0);
      a0 = fdot2u(w0v[q].z, hq.z, a0); a0 = fdot2u(w0v[q].w, hq.w, a0);
      a1 = fdot2u(w1v[q].x, hq.x, a1); a1 = fdot2u(w1v[q].y, hq.y, a1);
      a1 = fdot2u(w1v[q].z, hq.z, a1); a1 = fdot2u(w1v[q].w, hq.w, a1);
    }
#pragma unroll
    for (int q = 0; q < 8; ++q){
      uint4 hq = h2v[24+q];
      uint4 wa = lw4[r0*9+q];
      uint4 wb = lw4[r1*9+q];
      a0 = fdot2u(wa.x, hq.x, a0); a0 = fdot2u(wa.y, hq.y, a0);
      a0 = fdot2u(wa.z, hq.z, a0); a0 = fdot2u(wa.w, hq.w, a0);
      a1 = fdot2u(wb.x, hq.x, a1); a1 = fdot2u(wb.y, hq.y, a1);
      a1 = fdot2u(wb.z, hq.z, a1); a1 = fdot2u(wb.w, hq.w, a1);
    }
    gts[r0] = a0; gts[r1] = a1;

    // prefetch next x (threads 256..263, f/o-gate rows: they don't do the update)
    unsigned xpk = 0;
    bool doX = (j >= 256 && j < 264) && (t+1 < NT);
    if (doX){
      int i2 = j - 256; int k0 = 2*i2;
      const float* xp = seq + ((size_t)b*NT + (t+1))*NV;
      float xa = (k0   < NV)? xp[k0]   : 0.f;
      float xc2= (k0+1 < NV)? xp[k0+1] : 0.f;
      xpk = pk2(xa, xc2);
    }
    __syncthreads();
    if (j < 256){
      float gi = gts[j], gf = gts[j+256], gg = gts[j+512], go = gts[j+768];
      c = sigm(gf)*c + sigm(gi)*tanh_(gg);
      float h = sigm(go)*tanh_(c);
      __half hh = __float2half(h);
      ((__half*)h2)[j] = hh;
      hs[((size_t)b*NT + t)*NH + j] = hh;
    }
    if (doX) xb[(t+1) & 1][j-256] = xpk;
    __syncthreads();
  }
}

// ---------------- projection + loss: f16 MFMA GEMM (M=128 tile, N=256, K=384) ----------------
struct __align__(16) SMp {
  union {
    struct { __half As[128][72]; __half Bs[256][72]; } s;   // staged tiles (pad 64->72)
    __half Zs[128][264];                                    // relu output (pad 256->264)
  } u;
  unsigned wout[16][128];
  float bnl[256];
  float bout[16];
  float logit[128][16];
  float red[128];
};

__global__ __launch_bounds__(512, 2)
void k_proj(const unsigned char* __restrict__ ws,
            const int* __restrict__ labels, const int* __restrict__ lengths,
            const float* __restrict__ bnl, const float* __restrict__ bout,
            float* __restrict__ out){
  __shared__ SMp sm;
  int tid = threadIdx.x;
  int mt = blockIdx.x;
  int m0 = mt*128;
  int b  = m0 >> 10;
  int t0 = m0 & 1023;
  const __half* hs      = (const __half*)(ws + WS_HS);
  const unsigned* latf  = (const unsigned*)(ws + WS_LATF);
  const unsigned* wnl   = (const unsigned*)(ws + WS_WNL);
  const unsigned* woutg = (const unsigned*)(ws + WS_WOUT);

  for (int i = tid; i < 2048; i += 512) ((unsigned*)sm.wout)[i] = woutg[i];
  if (tid < 256) sm.bnl[tid] = bnl[tid];
  if (tid < 16)  sm.bout[tid] = (tid < NV)? bout[tid] : 0.f;

  int wave = tid >> 6, lane = tid & 63;
  int wm = wave >> 2, wn = wave & 3;        // 2 x 4 wave grid, 64x64 per wave
  int l15 = lane & 15, l4 = lane >> 4;

  f32x4 acc[4][4];
  f32x4 zz = {0.f,0.f,0.f,0.f};
#pragma unroll
  for (int a = 0; a < 4; ++a)
#pragma unroll
    for (int q = 0; q < 4; ++q) acc[a][q] = zz;

#pragma unroll 1
  for (int kt = 0; kt < 6; ++kt){
#pragma unroll
    for (int it = 0; it < 2; ++it){           // stage A: 128 rows x 64 k (f16)
      int idx = it*512 + tid;
      int r = idx >> 3, ck = idx & 7;
      int k = kt*64 + ck*8;
      uint4 val;
      if (k < 256) val = *(const uint4*)&hs[((size_t)(m0+r))*NH + k];
      else         val = *(const uint4*)&latf[b*64 + (k-256)/2];
      *(uint4*)&sm.u.s.As[r][ck*8] = val;
    }
#pragma unroll
    for (int it = 0; it < 4; ++it){           // stage B: W_nl 256 rows x 64 k
      int idx = it*512 + tid;
      int n = idx >> 3, ck = idx & 7;
      int k = kt*64 + ck*8;
      uint4 val = *(const uint4*)&wnl[n*192 + k/2];
      *(uint4*)&sm.u.s.Bs[n][ck*8] = val;
    }
    __syncthreads();
#pragma unroll
    for (int kk = 0; kk < 2; ++kk){
      f16x8 af[4], bf[4];
#pragma unroll
      for (int mf = 0; mf < 4; ++mf) af[mf] = *(const f16x8*)&sm.u.s.As[wm*64+mf*16+l15][kk*32+l4*8];
#pragma unroll
      for (int nf = 0; nf < 4; ++nf) bf[nf] = *(const f16x8*)&sm.u.s.Bs[wn*64+nf*16+l15][kk*32+l4*8];
#pragma unroll
      for (int mf = 0; mf < 4; ++mf)
#pragma unroll
        for (int nf = 0; nf < 4; ++nf)
          acc[mf][nf] = __builtin_amdgcn_mfma_f32_16x16x32_f16(af[mf], bf[nf], acc[mf][nf], 0, 0, 0);
    }
    __syncthreads();
  }

  // epilogue: bias + relu -> Zs (f16)
#pragma unroll
  for (int mf = 0; mf < 4; ++mf)
#pragma unroll
    for (int nf = 0; nf < 4; ++nf)
#pragma unroll
      for (int e = 0; e < 4; ++e){
        int row = wm*64 + mf*16 + l4*4 + e;
        int col = wn*64 + nf*16 + l15;
        float v = acc[mf][nf][e] + sm.bnl[col];
        v = v > 0.f ? v : 0.f;
        sm.u.Zs[row][col] = __float2half(v);
      }
  __syncthreads();

  // GEMV: logits[r][v] = Z[r,:] . W_out[v,:] + b_out[v]; 4 threads per row, 4 v's each
  int r = tid >> 2, q = tid & 3;
  float la0 = sm.bout[q], la1 = sm.bout[q+4], la2 = sm.bout[q+8], la3 = sm.bout[q+12];
#pragma unroll
  for (int c8 = 0; c8 < 32; ++c8){
    uint4 zv = *(const uint4*)&sm.u.Zs[r][c8*8];
    uint4 w0 = *(const uint4*)&sm.wout[q][c8*4];
    uint4 w1 = *(const uint4*)&sm.wout[q+4][c8*4];
    uint4 w2 = *(const uint4*)&sm.wout[q+8][c8*4];
    uint4 w3 = *(const uint4*)&sm.wout[q+12][c8*4];
    la0 = fdot2u(w0.x, zv.x, la0); la0 = fdot2u(w0.y, zv.y, la0);
    la0 = fdot2u(w0.z, zv.z, la0); la0 = fdot2u(w0.w, zv.w, la0);
    la1 = fdot2u(w1.x, zv.x, la1); la1 = fdot2u(w1.y, zv.y, la1);
    la1 = fdot2u(w1.z, zv.z, la1); la1 = fdot2u(w1.w, zv.w, la1);
    la2 = fdot2u(w2.x, zv.x, la2); la2 = fdot2u(w2.y, zv.y, la2);
    la2 = fdot2u(w2.z, zv.z, la2); la2 = fdot2u(w2.w, zv.w, la2);
    la3 = fdot2u(w3.x, zv.x, la3); la3 = fdot2u(w3.y, zv.y, la3);
    la3 = fdot2u(w3.z, zv.z, la3); la3 = fdot2u(w3.w, zv.w, la3);
  }
  sm.logit[r][q] = la0; sm.logit[r][q+4] = la1; sm.logit[r][q+8] = la2; sm.logit[r][q+12] = la3;
  __syncthreads();

  if (tid < 128){
    int t = t0 + tid;
    float mx = -1e30f;
#pragma unroll
    for (int v = 0; v < NV; ++v) mx = fmaxf(mx, sm.logit[tid][v]);
    float s = 0.f;
#pragma unroll
    for (int v = 0; v < NV; ++v) s += __expf(sm.logit[tid][v] - mx);
    float lse = mx + __logf(s);
    int lab = labels[b*NT + t];
    float nll = lse - sm.logit[tid][lab];
    sm.red[tid] = (t < lengths[b])? nll : 0.f;
  }
  __syncthreads();
  if (tid < 64){
    float v = sm.red[tid] + sm.red[tid+64];
#pragma unroll
    for (int off = 32; off > 0; off >>= 1) v += __shfl_down(v, off);
    if (tid == 0) atomicAdd(out + b, v);
  }
}

extern "C" void kernel_launch(void* const* d_in, const int* in_sizes, int n_in,
                              void* d_out, int out_size, void* d_ws, size_t ws_size,
                              hipStream_t stream){
  const float* seq   = (const float*)d_in[0];
  const float* lat   = (const float*)d_in[1];
  const int* labels  = (const int*)d_in[2];
  const int* lengths = (const int*)d_in[3];
  const float* Wlat  = (const float*)d_in[4];
  const float* blat  = (const float*)d_in[5];
  const float* Wih   = (const float*)d_in[6];
  const float* Whh   = (const float*)d_in[7];
  const float* bih   = (const float*)d_in[8];
  const float* bhh   = (const float*)d_in[9];
  const float* Wnl   = (const float*)d_in[10];
  const float* bnl   = (const float*)d_in[11];
  const float* Wout  = (const float*)d_in[12];
  const float* bout  = (const float*)d_in[13];
  float* out = (float*)d_out;
  unsigned char* ws = (unsigned char*)d_ws;

  hipLaunchKernelGGL(k_prep, dim3(1281), dim3(128), 0, stream, Wih, Whh, bih, bhh, Wnl, Wout, ws);
  hipLaunchKernelGGL(k_init, dim3(256), dim3(256), 0, stream, lat, Wlat, blat, ws, out);
  hipLaunchKernelGGL(k_lstm, dim3(256), dim3(512), 0, stream, seq, ws);
  hipLaunchKernelGGL(k_proj, dim3(2048), dim3(512), 0, stream, ws, labels, lengths, bnl, bout, out);
}